// Round 7
// baseline (123.459 us; speedup 1.0000x reference)
//
#include <hip/hip_runtime.h>

#define B_ 8
#define T_ 2048
#define C_ 1024
#define H_ 64

typedef __attribute__((ext_vector_type(8))) short short8;
typedef __attribute__((ext_vector_type(4))) float floatx4;
typedef __attribute__((ext_vector_type(4))) int intx4;

static __device__ __forceinline__ unsigned short f2bf(float f) {
  unsigned int u = __builtin_bit_cast(unsigned int, f);
  u += 0x7FFFu + ((u >> 16) & 1u);   // RNE
  return (unsigned short)(u >> 16);
}
static __device__ __forceinline__ float bf2f(unsigned short u) {
  return __builtin_bit_cast(float, ((unsigned int)u) << 16);
}
static __device__ __forceinline__ unsigned int fbits(float f) {
  return __builtin_bit_cast(unsigned int, f);
}

typedef const __attribute__((address_space(1))) unsigned int* gp1_t;
typedef __attribute__((address_space(3))) unsigned int* lp3_t;
static __device__ __forceinline__ void gl_lds16(const void* g, void* l) {
  __builtin_amdgcn_global_load_lds((gp1_t)g, (lp3_t)l, 16, 0, 0);
}

// ---------------------------------------------------------------------------
// Kernel 0: W fp32 -> Wf FRAGMENT-READY bf16 (unchanged).
// ---------------------------------------------------------------------------
__global__ __launch_bounds__(256) void conv_w(const float* __restrict__ wq,
    const float* __restrict__ wk, const float* __restrict__ wv,
    unsigned short* __restrict__ wf) {
  int c = blockIdx.x * 256 + threadIdx.x;   // 24576 chunks
  int lane = c & 63;
  int t = c >> 6;
  int ng = t % 12;
  int kk = t / 12;                           // kt*2+ks, 0..31
  int k0 = kk * 32 + (lane >> 4) * 8;
  int n = ng * 16 + (lane & 15);
  const float* src;
  int col;
  float scale = 1.0f;
  if (n < 64)       { src = wq; col = n;       scale = 0.03125f * 1.44269504088896340736f; }
  else if (n < 128) { src = wk; col = n - 64;  }
  else              { src = wv; col = n - 128; }
  unsigned short o[8];
#pragma unroll
  for (int j = 0; j < 8; ++j) o[j] = f2bf(src[(size_t)(k0 + j) * H_ + col] * scale);
  *(uint4*)&wf[(size_t)c * 8] = *(const uint4*)o;
}

// ---------------------------------------------------------------------------
// Kernel 1: QKV projection (unchanged this round; isolating the attn change).
// V epilogue writes Vf k-PERMUTED to match the swapped-QK^T P fragment.
// ---------------------------------------------------------------------------
__global__ __launch_bounds__(256, 4) void qkv_proj(
    const float* __restrict__ x, const unsigned short* __restrict__ wf,
    unsigned short* __restrict__ qo, unsigned short* __restrict__ kf,
    unsigned short* __restrict__ vf) {
  __shared__ float XL[2][4096];   // 2 x (32 rows x 128 fp32) = 32 KB
  int tid = threadIdx.x;
  int wave = tid >> 6, lane = tid & 63;
  int lane4 = lane & 15, quad = lane >> 4;
  int m0 = blockIdx.x * 32;
  int ph0 = blockIdx.x & 7;       // per-block K-order rotation

  // stage one phase (32 rows x 128 floats = 1024 16B-chunks, 4 insts/thread)
  auto stage_ph = [&](int phr, int buf) {
#pragma unroll
    for (int j = 0; j < 4; ++j) {
      int c = (wave * 4 + j) * 64 + lane;    // chunk id 0..1023
      int r = c >> 5, pc = c & 31;           // 32 chunks per row
      int cl = (pc & ~7) | ((pc ^ (r & 7)) & 7);
      gl_lds16(&x[(size_t)(m0 + r) * C_ + phr * 128 + cl * 4], &XL[buf][c * 4]);
    }
  };

  floatx4 acc[2][3];
#pragma unroll
  for (int mt = 0; mt < 2; ++mt)
#pragma unroll
    for (int nt = 0; nt < 3; ++nt) acc[mt][nt] = (floatx4)0.0f;

  stage_ph(ph0, 0);
  __syncthreads();

  for (int ph = 0; ph < 8; ++ph) {
    int buf = ph & 1;
    if (ph < 7) stage_ph((ph + 1 + ph0) & 7, buf ^ 1);   // async prefetch
    int phr = (ph + ph0) & 7;
#pragma unroll
    for (int sl = 0; sl < 4; ++sl) {
      int s = phr * 4 + sl;            // global ks-step, 0..31
      short8 b[3];
#pragma unroll
      for (int nt = 0; nt < 3; ++nt)
        b[nt] = *(const short8*)&wf[(size_t)(s * 12 + wave * 3 + nt) * 512 + lane * 8];
      short8 a[2];
#pragma unroll
      for (int mt = 0; mt < 2; ++mt) {
        int r = mt * 16 + lane4;
        int c0 = sl * 8 + quad * 2;    // phase-local float4-chunk, 0..31
        int pc0 = (c0 & ~7) | ((c0 ^ (r & 7)) & 7);
        int pc1 = ((c0 + 1) & ~7) | (((c0 + 1) ^ (r & 7)) & 7);
        float4 f0 = *(const float4*)&XL[buf][r * 128 + pc0 * 4];
        float4 f1 = *(const float4*)&XL[buf][r * 128 + pc1 * 4];
        intx4 pk;
        pk[0] = (int)__builtin_amdgcn_perm(fbits(f0.y), fbits(f0.x), 0x07060302u);
        pk[1] = (int)__builtin_amdgcn_perm(fbits(f0.w), fbits(f0.z), 0x07060302u);
        pk[2] = (int)__builtin_amdgcn_perm(fbits(f1.y), fbits(f1.x), 0x07060302u);
        pk[3] = (int)__builtin_amdgcn_perm(fbits(f1.w), fbits(f1.z), 0x07060302u);
        a[mt] = __builtin_bit_cast(short8, pk);
      }
#pragma unroll
      for (int mt = 0; mt < 2; ++mt)
#pragma unroll
        for (int nt = 0; nt < 3; ++nt)
          acc[mt][nt] = __builtin_amdgcn_mfma_f32_16x16x32_bf16(a[mt], b[nt], acc[mt][nt], 0, 0, 0);
    }
    __syncthreads();   // prefetch landed + all waves done with buf
  }

  // ---- epilogue: q direct; K,V via LDS into fragment-ready layouts ----
  unsigned short* VTB = (unsigned short*)&XL[0][0];   // [64 h][40] bf16 (V^T)
  unsigned short* KB  = VTB + 5120;                   // [32 t][72] bf16
#pragma unroll
  for (int mt = 0; mt < 2; ++mt)
#pragma unroll
    for (int nt = 0; nt < 3; ++nt) {
      int n = wave * 48 + nt * 16 + lane4;
#pragma unroll
      for (int rr = 0; rr < 4; ++rr) {
        unsigned short val = f2bf(acc[mt][nt][rr]);
        int lrow = mt * 16 + quad * 4 + rr;
        if (n < 64)       qo[(size_t)(m0 + lrow) * H_ + n] = val;
        else if (n < 128) KB[lrow * 72 + (n - 64)] = val;
        else              VTB[(n - 128) * 40 + lrow] = val;
      }
    }
  __syncthreads();
  {
    int bb = m0 >> 11, t0 = m0 & 2047;
    int st = t0 >> 6, off = t0 & 63;
    // K: 256 chunks (ks x ctl x 64 lanes)
    int ks = tid >> 7, ctl = (tid >> 6) & 1, ln = tid & 63;
    int ct = (off >> 4) + ctl;
    int tl = ctl * 16 + (ln & 15);
    int h0 = ks * 32 + (ln >> 4) * 8;
    uint4 kd = *(const uint4*)&KB[tl * 72 + h0];
    *(uint4*)&kf[((size_t)((bb * 32 + st) * 2 + ks) * 4 + ct) * 512 + ln * 8] = kd;
    // V: 256 chunks (nt x 64 lanes), ks fixed = off>>5; k-permuted frag:
    // slot (qs, j<4) = t 4*qs+j ; slot (qs, j>=4) = t 16+4*qs+(j-4)
    int nt = tid >> 6, l4 = tid & 15, qs = (tid >> 4) & 3;
    int ksv = off >> 5;
    uint2 vlo = *(const uint2*)&VTB[(nt * 16 + l4) * 40 + qs * 4];
    uint2 vhi = *(const uint2*)&VTB[(nt * 16 + l4) * 40 + 16 + qs * 4];
    uint4 vd = make_uint4(vlo.x, vlo.y, vhi.x, vhi.y);
    *(uint4*)&vf[((size_t)((bb * 32 + st) * 2 + ksv) * 4 + nt) * 512 + (tid & 63) * 8] = vd;
  }
}

// ---------------------------------------------------------------------------
// Kernel 2: causal flash attention, split-4, in-register fixed-max softmax,
// counted-vmcnt 3-buffer pipeline (R19).
// R20 CHANGE (dispatch-order-INDEPENDENT balance): R19's neutral result
// killed the exposed-latency theory; the remaining candidate for the ~28Kcy
// unexplained per-CU time is that R18's breadth-first c/c+256 pairing
// assumption only half-holds. Now each block processes qt=q THEN qt=15-q
// sequentially: tiles/block = (2q+2)/4 + (2(15-q)+2)/4 = 36/4 = EXACTLY 9
// for every block, independent of the dispatcher. Grid (8,8,4) = 256 blocks
// = 1/CU. Per-tile code, staging, Op layout and merge untouched. Cost:
// 2 waves/SIMD instead of 4 (counted-vmcnt prefetch + setprio mitigate)
// and one __syncthreads between parts (drains part-A tail stages once).
// In-flight A-tail gl_lds vs B-prologue writes to the same buffer are safe:
// vmcnt retires in order, so the younger (B) write lands last, and B's
// vmcnt(2) precedes any read of its buffers.
// ---------------------------------------------------------------------------
__global__ __launch_bounds__(512, 4) void attn(
    const unsigned short* __restrict__ qi, const unsigned short* __restrict__ Kf,
    const unsigned short* __restrict__ Vf, unsigned short* __restrict__ Op,
    float* __restrict__ lsum) {
  __shared__ unsigned short KV[3][8192];   // [buf][ K: 0..4095 | V: 4096..8191 ]

  int tid = threadIdx.x;
  int wave = tid >> 6, lane = tid & 63;
  int lane4 = lane & 15, quad = lane >> 4;
  int q = (int)blockIdx.x;        // pair id 0..7 -> handles qt = q and 15-q
  int b = blockIdx.y, split = blockIdx.z;
  int base = b * T_;

  // stage one 64-row K/V tile (8 KB + 8 KB) into KV[bf]; 2 insts/thread.
  auto stage = [&](int st, int bf) {
    size_t tb = (size_t)(b * 32 + st) * 4096;
    gl_lds16(&Kf[tb + (size_t)tid * 8], &KV[bf][tid * 8]);
    gl_lds16(&Vf[tb + (size_t)tid * 8], &KV[bf][4096 + tid * 8]);
  };

#pragma unroll 1
  for (int part = 0; part < 2; ++part) {
    int qt = part ? (15 - q) : q;
    int qb = qt * 128;

    int ntile = 2 * qt + 2;
    int sBeg = (split * ntile) >> 2;
    int sEnd = ((split + 1) * ntile) >> 2;
    int last = sEnd - 1;

    if (part) __syncthreads();   // all waves done reading part-0 buffers

    short8 aq[2];
#pragma unroll
    for (int ks = 0; ks < 2; ++ks)
      aq[ks] = *(const short8*)&qi[(size_t)(base + qb + wave * 16 + lane4) * H_ + ks * 32 + quad * 8];

    float lsumv = 0.0f;
    floatx4 o[4];
#pragma unroll
    for (int nt = 0; nt < 4; ++nt) o[nt] = (floatx4)0.0f;

    if (sBeg < sEnd) {
      // depth-2 prologue (clamped: redundant re-stage keeps counts uniform)
      stage(sBeg, 0);
      {
        int s1 = sBeg + 1 <= last ? sBeg + 1 : last;
        stage(s1, 1);
      }

      for (int it = 0; it < sEnd - sBeg; ++it) {
        int st = sBeg + it;
        int buf = it % 3;

        // stage(st) landed (>=2 newer gl_lds exist); align all waves.
        asm volatile("s_waitcnt vmcnt(2)" ::: "memory");
        __builtin_amdgcn_sched_barrier(0);
        __builtin_amdgcn_s_barrier();

        // issue stage(st+2): overwrites the buffer last read in iter it-1,
        // which every wave finished before the barrier above.
        {
          int s2 = st + 2 <= last ? st + 2 : last;
          stage(s2, (it + 2) % 3);
        }

        // S^T = K . Q^T : lane holds S[kcol = ct*16+quad*4+r][qrow = lane4]
        floatx4 sacc[4];
#pragma unroll
        for (int ct = 0; ct < 4; ++ct) sacc[ct] = (floatx4)0.0f;
        __builtin_amdgcn_s_setprio(1);
#pragma unroll
        for (int ks = 0; ks < 2; ++ks)
#pragma unroll
          for (int ct = 0; ct < 4; ++ct) {
            short8 bk = *(const short8*)&KV[buf][(ks * 4 + ct) * 512 + lane * 8];
            sacc[ct] = __builtin_amdgcn_mfma_f32_16x16x32_bf16(bk, aq[ks], sacc[ct], 0, 0, 0);
          }
        __builtin_amdgcn_s_setprio(0);

        if (st >= 2 * qt) {   // the two diagonal-crossing tiles: absolute mask
          int qrow = qb + wave * 16 + lane4;
#pragma unroll
          for (int ct = 0; ct < 4; ++ct)
#pragma unroll
            for (int r = 0; r < 4; ++r) {
              int scol = st * 64 + ct * 16 + quad * 4 + r;
              if (scol > qrow) sacc[ct][r] = -3.0e38f;
            }
        }

        // fixed-max softmax in registers: p = exp2(s - 8); pack via perm
        unsigned int pk[4][2];
#pragma unroll
        for (int ct = 0; ct < 4; ++ct) {
          float p0 = exp2f(sacc[ct][0] - 8.0f);
          float p1 = exp2f(sacc[ct][1] - 8.0f);
          float p2 = exp2f(sacc[ct][2] - 8.0f);
          float p3 = exp2f(sacc[ct][3] - 8.0f);
          lsumv += (p0 + p1) + (p2 + p3);
          pk[ct][0] = __builtin_amdgcn_perm(fbits(p1), fbits(p0), 0x07060302u);
          pk[ct][1] = __builtin_amdgcn_perm(fbits(p3), fbits(p2), 0x07060302u);
        }

        // O += P V  (pa register-resident; Vf k-order matches pk layout)
        __builtin_amdgcn_s_setprio(1);
#pragma unroll
        for (int ks = 0; ks < 2; ++ks) {
          intx4 pai;
          pai[0] = (int)pk[2 * ks][0];
          pai[1] = (int)pk[2 * ks][1];
          pai[2] = (int)pk[2 * ks + 1][0];
          pai[3] = (int)pk[2 * ks + 1][1];
          short8 pa = __builtin_bit_cast(short8, pai);
#pragma unroll
          for (int nt = 0; nt < 4; ++nt) {
            short8 bv = *(const short8*)&KV[buf][4096 + (ks * 4 + nt) * 512 + lane * 8];
            o[nt] = __builtin_amdgcn_mfma_f32_16x16x32_bf16(pa, bv, o[nt], 0, 0, 0);
          }
        }
        __builtin_amdgcn_s_setprio(0);
      }
    }

    // l-reduce: quads {0,1,2,3} of each lane4 hold partials of the same row
    lsumv += __shfl_xor(lsumv, 16);
    lsumv += __shfl_xor(lsumv, 32);

    size_t pbase = (((size_t)split * 8 + b) * 16 + qt) * 128;
#pragma unroll
    for (int r = 0; r < 4; ++r) {
      int row = wave * 16 + quad * 4 + r;
#pragma unroll
      for (int nt = 0; nt < 4; ++nt)
        Op[(pbase + row) * 64 + nt * 16 + lane4] = f2bf(o[nt][r]);
    }
    if (quad == 0) lsum[pbase + wave * 16 + lane4] = lsumv;
  }
}

// ---------------------------------------------------------------------------
// Kernel 3: merge the 4 key-range splits: out = sum(O_i) / sum(l_i).
// (unchanged; 128-row q-block indexing)
// ---------------------------------------------------------------------------
__global__ __launch_bounds__(256) void merge_splits(
    const unsigned short* __restrict__ Op, const float* __restrict__ lsum,
    float* __restrict__ out) {
  int idx = blockIdx.x * 256 + threadIdx.x;
  int row = idx >> 4;
  int h4 = (idx & 15) * 4;
  int b = row >> 11, t = row & 2047;
  int qt = t >> 7, r = t & 127;
  float O0 = 0.f, O1 = 0.f, O2 = 0.f, O3 = 0.f, l = 0.f;
#pragma unroll
  for (int s = 0; s < 4; ++s) {
    size_t p = (((size_t)s * 8 + b) * 16 + qt) * 128 + r;
    l += lsum[p];
    ushort4 ov = *(const ushort4*)&Op[p * 64 + h4];
    O0 += bf2f(ov.x); O1 += bf2f(ov.y); O2 += bf2f(ov.z); O3 += bf2f(ov.w);
  }
  float inv = 1.0f / l;
  float4 res = make_float4(O0 * inv, O1 * inv, O2 * inv, O3 * inv);
  *(float4*)&out[(size_t)row * H_ + h4] = res;
}

extern "C" void kernel_launch(void* const* d_in, const int* in_sizes, int n_in,
                              void* d_out, int out_size, void* d_ws, size_t ws_size,
                              hipStream_t stream) {
  const float* x  = (const float*)d_in[0];
  const float* wq = (const float*)d_in[1];
  const float* wk = (const float*)d_in[2];
  const float* wv = (const float*)d_in[3];
  float* out = (float*)d_out;

  char* ws = (char*)d_ws;
  unsigned short* wf = (unsigned short*)ws;                    // 393216 B
  unsigned short* qb = (unsigned short*)(ws + 393216);         // 2097152 B
  unsigned short* kf = (unsigned short*)(ws + 2490368);        // 2097152 B (frag-ready)
  unsigned short* vf = (unsigned short*)(ws + 4587520);        // 2097152 B (frag-ready)
  unsigned short* Op = (unsigned short*)(ws + 6684672);        // 8388608 B (4 splits)
  float*          ls = (float*)(ws + 15073280);                // 262144 B (total 15335424)

  conv_w<<<96, 256, 0, stream>>>(wq, wk, wv, wf);
  qkv_proj<<<512, 256, 0, stream>>>(x, wf, qb, kf, vf);
  attn<<<dim3(8, 8, 4), 512, 0, stream>>>(qb, kf, vf, Op, ls);
  merge_splits<<<1024, 256, 0, stream>>>(Op, ls, out);
}

// Round 8
// 123.206 us; speedup vs baseline: 1.0021x; 1.0021x over previous
//
#include <hip/hip_runtime.h>

#define B_ 8
#define T_ 2048
#define C_ 1024
#define H_ 64

typedef __attribute__((ext_vector_type(8))) short short8;
typedef __attribute__((ext_vector_type(4))) float floatx4;
typedef __attribute__((ext_vector_type(4))) int intx4;

static __device__ __forceinline__ unsigned short f2bf(float f) {
  unsigned int u = __builtin_bit_cast(unsigned int, f);
  u += 0x7FFFu + ((u >> 16) & 1u);   // RNE
  return (unsigned short)(u >> 16);
}
static __device__ __forceinline__ float bf2f(unsigned short u) {
  return __builtin_bit_cast(float, ((unsigned int)u) << 16);
}
static __device__ __forceinline__ unsigned int fbits(float f) {
  return __builtin_bit_cast(unsigned int, f);
}

typedef const __attribute__((address_space(1))) unsigned int* gp1_t;
typedef __attribute__((address_space(3))) unsigned int* lp3_t;
static __device__ __forceinline__ void gl_lds16(const void* g, void* l) {
  __builtin_amdgcn_global_load_lds((gp1_t)g, (lp3_t)l, 16, 0, 0);
}

// ---------------------------------------------------------------------------
// Kernel 0: W fp32 -> Wf FRAGMENT-READY bf16 (unchanged).
// ---------------------------------------------------------------------------
__global__ __launch_bounds__(256) void conv_w(const float* __restrict__ wq,
    const float* __restrict__ wk, const float* __restrict__ wv,
    unsigned short* __restrict__ wf) {
  int c = blockIdx.x * 256 + threadIdx.x;   // 24576 chunks
  int lane = c & 63;
  int t = c >> 6;
  int ng = t % 12;
  int kk = t / 12;                           // kt*2+ks, 0..31
  int k0 = kk * 32 + (lane >> 4) * 8;
  int n = ng * 16 + (lane & 15);
  const float* src;
  int col;
  float scale = 1.0f;
  if (n < 64)       { src = wq; col = n;       scale = 0.03125f * 1.44269504088896340736f; }
  else if (n < 128) { src = wk; col = n - 64;  }
  else              { src = wv; col = n - 128; }
  unsigned short o[8];
#pragma unroll
  for (int j = 0; j < 8; ++j) o[j] = f2bf(src[(size_t)(k0 + j) * H_ + col] * scale);
  *(uint4*)&wf[(size_t)c * 8] = *(const uint4*)o;
}

// ---------------------------------------------------------------------------
// Kernel 1: QKV projection (unchanged this round; isolating the attn change).
// V epilogue writes Vf k-PERMUTED to match the swapped-QK^T P fragment.
// ---------------------------------------------------------------------------
__global__ __launch_bounds__(256, 4) void qkv_proj(
    const float* __restrict__ x, const unsigned short* __restrict__ wf,
    unsigned short* __restrict__ qo, unsigned short* __restrict__ kf,
    unsigned short* __restrict__ vf) {
  __shared__ float XL[2][4096];   // 2 x (32 rows x 128 fp32) = 32 KB
  int tid = threadIdx.x;
  int wave = tid >> 6, lane = tid & 63;
  int lane4 = lane & 15, quad = lane >> 4;
  int m0 = blockIdx.x * 32;
  int ph0 = blockIdx.x & 7;       // per-block K-order rotation

  // stage one phase (32 rows x 128 floats = 1024 16B-chunks, 4 insts/thread)
  auto stage_ph = [&](int phr, int buf) {
#pragma unroll
    for (int j = 0; j < 4; ++j) {
      int c = (wave * 4 + j) * 64 + lane;    // chunk id 0..1023
      int r = c >> 5, pc = c & 31;           // 32 chunks per row
      int cl = (pc & ~7) | ((pc ^ (r & 7)) & 7);
      gl_lds16(&x[(size_t)(m0 + r) * C_ + phr * 128 + cl * 4], &XL[buf][c * 4]);
    }
  };

  floatx4 acc[2][3];
#pragma unroll
  for (int mt = 0; mt < 2; ++mt)
#pragma unroll
    for (int nt = 0; nt < 3; ++nt) acc[mt][nt] = (floatx4)0.0f;

  stage_ph(ph0, 0);
  __syncthreads();

  for (int ph = 0; ph < 8; ++ph) {
    int buf = ph & 1;
    if (ph < 7) stage_ph((ph + 1 + ph0) & 7, buf ^ 1);   // async prefetch
    int phr = (ph + ph0) & 7;
#pragma unroll
    for (int sl = 0; sl < 4; ++sl) {
      int s = phr * 4 + sl;            // global ks-step, 0..31
      short8 b[3];
#pragma unroll
      for (int nt = 0; nt < 3; ++nt)
        b[nt] = *(const short8*)&wf[(size_t)(s * 12 + wave * 3 + nt) * 512 + lane * 8];
      short8 a[2];
#pragma unroll
      for (int mt = 0; mt < 2; ++mt) {
        int r = mt * 16 + lane4;
        int c0 = sl * 8 + quad * 2;    // phase-local float4-chunk, 0..31
        int pc0 = (c0 & ~7) | ((c0 ^ (r & 7)) & 7);
        int pc1 = ((c0 + 1) & ~7) | (((c0 + 1) ^ (r & 7)) & 7);
        float4 f0 = *(const float4*)&XL[buf][r * 128 + pc0 * 4];
        float4 f1 = *(const float4*)&XL[buf][r * 128 + pc1 * 4];
        intx4 pk;
        pk[0] = (int)__builtin_amdgcn_perm(fbits(f0.y), fbits(f0.x), 0x07060302u);
        pk[1] = (int)__builtin_amdgcn_perm(fbits(f0.w), fbits(f0.z), 0x07060302u);
        pk[2] = (int)__builtin_amdgcn_perm(fbits(f1.y), fbits(f1.x), 0x07060302u);
        pk[3] = (int)__builtin_amdgcn_perm(fbits(f1.w), fbits(f1.z), 0x07060302u);
        a[mt] = __builtin_bit_cast(short8, pk);
      }
#pragma unroll
      for (int mt = 0; mt < 2; ++mt)
#pragma unroll
        for (int nt = 0; nt < 3; ++nt)
          acc[mt][nt] = __builtin_amdgcn_mfma_f32_16x16x32_bf16(a[mt], b[nt], acc[mt][nt], 0, 0, 0);
    }
    __syncthreads();   // prefetch landed + all waves done with buf
  }

  // ---- epilogue: q direct; K,V via LDS into fragment-ready layouts ----
  unsigned short* VTB = (unsigned short*)&XL[0][0];   // [64 h][40] bf16 (V^T)
  unsigned short* KB  = VTB + 5120;                   // [32 t][72] bf16
#pragma unroll
  for (int mt = 0; mt < 2; ++mt)
#pragma unroll
    for (int nt = 0; nt < 3; ++nt) {
      int n = wave * 48 + nt * 16 + lane4;
#pragma unroll
      for (int rr = 0; rr < 4; ++rr) {
        unsigned short val = f2bf(acc[mt][nt][rr]);
        int lrow = mt * 16 + quad * 4 + rr;
        if (n < 64)       qo[(size_t)(m0 + lrow) * H_ + n] = val;
        else if (n < 128) KB[lrow * 72 + (n - 64)] = val;
        else              VTB[(n - 128) * 40 + lrow] = val;
      }
    }
  __syncthreads();
  {
    int bb = m0 >> 11, t0 = m0 & 2047;
    int st = t0 >> 6, off = t0 & 63;
    // K: 256 chunks (ks x ctl x 64 lanes)
    int ks = tid >> 7, ctl = (tid >> 6) & 1, ln = tid & 63;
    int ct = (off >> 4) + ctl;
    int tl = ctl * 16 + (ln & 15);
    int h0 = ks * 32 + (ln >> 4) * 8;
    uint4 kd = *(const uint4*)&KB[tl * 72 + h0];
    *(uint4*)&kf[((size_t)((bb * 32 + st) * 2 + ks) * 4 + ct) * 512 + ln * 8] = kd;
    // V: 256 chunks (nt x 64 lanes), ks fixed = off>>5; k-permuted frag:
    // slot (qs, j<4) = t 4*qs+j ; slot (qs, j>=4) = t 16+4*qs+(j-4)
    int nt = tid >> 6, l4 = tid & 15, qs = (tid >> 4) & 3;
    int ksv = off >> 5;
    uint2 vlo = *(const uint2*)&VTB[(nt * 16 + l4) * 40 + qs * 4];
    uint2 vhi = *(const uint2*)&VTB[(nt * 16 + l4) * 40 + 16 + qs * 4];
    uint4 vd = make_uint4(vlo.x, vlo.y, vhi.x, vhi.y);
    *(uint4*)&vf[((size_t)((bb * 32 + st) * 2 + ksv) * 4 + nt) * 512 + (tid & 63) * 8] = vd;
  }
}

// ---------------------------------------------------------------------------
// Kernel 2: causal flash attention, split-4, in-register fixed-max softmax,
// counted-vmcnt 3-buffer pipeline (R19), qt<->15-qt dispatch pairing (R18,
// restored -- R20's 1-block/CU sequential pairing regressed).
// R21 CHANGE (2 q-stripes per wave = ILP-for-TLP swap): each wave now owns
// 32 q-rows (two 16-row stripes), 4 waves x 256 threads per block. Every
// bk/bv ds_read_b128 feeds TWO MFMAs (one per stripe) -> LDS reads per
// tile-instance halve (128 -> 64 b128/block) and each wave carries 2
// independent QK->softmax->PV chains. Same 4 chains/SIMD as R19, half the
// LDS issue. Staging: 4 gl_lds/thread -> loop wait becomes vmcnt(4)
// (stage(t) retired when only stage(t+1)'s 4 remain; in-order retirement).
// VGPR ~120, launch_bounds(256,2): no spill, all indices compile-time.
// Risk accepted: waves/CU 16 -> 8; if TLP (not LDS issue) was binding,
// this regresses like R20 and cleanly isolates the constraint.
// ---------------------------------------------------------------------------
__global__ __launch_bounds__(256, 2) void attn(
    const unsigned short* __restrict__ qi, const unsigned short* __restrict__ Kf,
    const unsigned short* __restrict__ Vf, unsigned short* __restrict__ Op,
    float* __restrict__ lsum) {
  __shared__ unsigned short KV[3][8192];   // [buf][ K: 0..4095 | V: 4096..8191 ]

  int tid = threadIdx.x;
  int wave = tid >> 6, lane = tid & 63;
  int lane4 = lane & 15, quad = lane >> 4;
  int split = blockIdx.z;
  int qt = (split < 2) ? (15 - (int)blockIdx.x) : (int)blockIdx.x;
  int b = blockIdx.y;
  int qb = qt * 128;
  int base = b * T_;

  int ntile = 2 * qt + 2;
  int sBeg = (split * ntile) >> 2;
  int sEnd = ((split + 1) * ntile) >> 2;
  int last = sEnd - 1;

  short8 aq[2][2];
#pragma unroll
  for (int sp = 0; sp < 2; ++sp)
#pragma unroll
    for (int ks = 0; ks < 2; ++ks)
      aq[sp][ks] = *(const short8*)&qi[(size_t)(base + qb + wave * 32 + sp * 16 + lane4) * H_ + ks * 32 + quad * 8];

  float lsumv0 = 0.0f, lsumv1 = 0.0f;
  floatx4 o[2][4];
#pragma unroll
  for (int sp = 0; sp < 2; ++sp)
#pragma unroll
    for (int nt = 0; nt < 4; ++nt) o[sp][nt] = (floatx4)0.0f;

  // stage one 64-row K/V tile (8 KB + 8 KB) into KV[bf]; 4 insts/thread.
  auto stage = [&](int st, int bf) {
    size_t tb = (size_t)(b * 32 + st) * 4096;
    gl_lds16(&Kf[tb + (size_t)tid * 8], &KV[bf][tid * 8]);
    gl_lds16(&Kf[tb + (size_t)(tid + 256) * 8], &KV[bf][(tid + 256) * 8]);
    gl_lds16(&Vf[tb + (size_t)tid * 8], &KV[bf][4096 + tid * 8]);
    gl_lds16(&Vf[tb + (size_t)(tid + 256) * 8], &KV[bf][4096 + (tid + 256) * 8]);
  };

  if (sBeg < sEnd) {
    // depth-2 prologue (clamped: redundant re-stage keeps counts uniform)
    stage(sBeg, 0);
    {
      int s1 = sBeg + 1 <= last ? sBeg + 1 : last;
      stage(s1, 1);
    }

    for (int it = 0; it < sEnd - sBeg; ++it) {
      int st = sBeg + it;
      int buf = it % 3;

      // stage(st) landed when only stage(st+1)'s 4 loads remain outstanding.
      asm volatile("s_waitcnt vmcnt(4)" ::: "memory");
      __builtin_amdgcn_sched_barrier(0);
      __builtin_amdgcn_s_barrier();

      // issue stage(st+2): overwrites the buffer last read in iter it-1,
      // which every wave finished before the barrier above.
      {
        int s2 = st + 2 <= last ? st + 2 : last;
        stage(s2, (it + 2) % 3);
      }

      // S^T = K . Q^T : lane holds S[kcol = ct*16+quad*4+r][qrow = lane4]
      // for both stripes; bk shared across stripes.
      floatx4 sacc[2][4];
#pragma unroll
      for (int sp = 0; sp < 2; ++sp)
#pragma unroll
        for (int ct = 0; ct < 4; ++ct) sacc[sp][ct] = (floatx4)0.0f;
      __builtin_amdgcn_s_setprio(1);
#pragma unroll
      for (int ks = 0; ks < 2; ++ks)
#pragma unroll
        for (int ct = 0; ct < 4; ++ct) {
          short8 bk = *(const short8*)&KV[buf][(ks * 4 + ct) * 512 + lane * 8];
          sacc[0][ct] = __builtin_amdgcn_mfma_f32_16x16x32_bf16(bk, aq[0][ks], sacc[0][ct], 0, 0, 0);
          sacc[1][ct] = __builtin_amdgcn_mfma_f32_16x16x32_bf16(bk, aq[1][ks], sacc[1][ct], 0, 0, 0);
        }
      __builtin_amdgcn_s_setprio(0);

      if (st >= 2 * qt) {   // the two diagonal-crossing tiles: absolute mask
#pragma unroll
        for (int sp = 0; sp < 2; ++sp) {
          int qrow = qb + wave * 32 + sp * 16 + lane4;
#pragma unroll
          for (int ct = 0; ct < 4; ++ct)
#pragma unroll
            for (int r = 0; r < 4; ++r) {
              int scol = st * 64 + ct * 16 + quad * 4 + r;
              if (scol > qrow) sacc[sp][ct][r] = -3.0e38f;
            }
        }
      }

      // fixed-max softmax in registers: p = exp2(s - 8); pack via perm
      unsigned int pk[2][4][2];
#pragma unroll
      for (int sp = 0; sp < 2; ++sp)
#pragma unroll
        for (int ct = 0; ct < 4; ++ct) {
          float p0 = exp2f(sacc[sp][ct][0] - 8.0f);
          float p1 = exp2f(sacc[sp][ct][1] - 8.0f);
          float p2 = exp2f(sacc[sp][ct][2] - 8.0f);
          float p3 = exp2f(sacc[sp][ct][3] - 8.0f);
          if (sp == 0) lsumv0 += (p0 + p1) + (p2 + p3);
          else         lsumv1 += (p0 + p1) + (p2 + p3);
          pk[sp][ct][0] = __builtin_amdgcn_perm(fbits(p1), fbits(p0), 0x07060302u);
          pk[sp][ct][1] = __builtin_amdgcn_perm(fbits(p3), fbits(p2), 0x07060302u);
        }

      // O += P V  (pa register-resident; Vf k-order matches pk layout;
      // bv shared across stripes)
      __builtin_amdgcn_s_setprio(1);
#pragma unroll
      for (int ks = 0; ks < 2; ++ks) {
        intx4 pai0, pai1;
        pai0[0] = (int)pk[0][2 * ks][0];
        pai0[1] = (int)pk[0][2 * ks][1];
        pai0[2] = (int)pk[0][2 * ks + 1][0];
        pai0[3] = (int)pk[0][2 * ks + 1][1];
        pai1[0] = (int)pk[1][2 * ks][0];
        pai1[1] = (int)pk[1][2 * ks][1];
        pai1[2] = (int)pk[1][2 * ks + 1][0];
        pai1[3] = (int)pk[1][2 * ks + 1][1];
        short8 pa0 = __builtin_bit_cast(short8, pai0);
        short8 pa1 = __builtin_bit_cast(short8, pai1);
#pragma unroll
        for (int nt = 0; nt < 4; ++nt) {
          short8 bv = *(const short8*)&KV[buf][4096 + (ks * 4 + nt) * 512 + lane * 8];
          o[0][nt] = __builtin_amdgcn_mfma_f32_16x16x32_bf16(pa0, bv, o[0][nt], 0, 0, 0);
          o[1][nt] = __builtin_amdgcn_mfma_f32_16x16x32_bf16(pa1, bv, o[1][nt], 0, 0, 0);
        }
      }
      __builtin_amdgcn_s_setprio(0);
    }
  }

  // l-reduce: quads {0,1,2,3} of each lane4 hold partials of the same q-row
  lsumv0 += __shfl_xor(lsumv0, 16);
  lsumv0 += __shfl_xor(lsumv0, 32);
  lsumv1 += __shfl_xor(lsumv1, 16);
  lsumv1 += __shfl_xor(lsumv1, 32);

  size_t pbase = (((size_t)split * 8 + b) * 16 + qt) * 128;
#pragma unroll
  for (int sp = 0; sp < 2; ++sp)
#pragma unroll
    for (int r = 0; r < 4; ++r) {
      int row = wave * 32 + sp * 16 + quad * 4 + r;
#pragma unroll
      for (int nt = 0; nt < 4; ++nt)
        Op[(pbase + row) * 64 + nt * 16 + lane4] = f2bf(o[sp][nt][r]);
    }
  if (quad == 0) {
    lsum[pbase + wave * 32 + lane4] = lsumv0;
    lsum[pbase + wave * 32 + 16 + lane4] = lsumv1;
  }
}

// ---------------------------------------------------------------------------
// Kernel 3: merge the 4 key-range splits: out = sum(O_i) / sum(l_i).
// (unchanged; 128-row q-block indexing)
// ---------------------------------------------------------------------------
__global__ __launch_bounds__(256) void merge_splits(
    const unsigned short* __restrict__ Op, const float* __restrict__ lsum,
    float* __restrict__ out) {
  int idx = blockIdx.x * 256 + threadIdx.x;
  int row = idx >> 4;
  int h4 = (idx & 15) * 4;
  int b = row >> 11, t = row & 2047;
  int qt = t >> 7, r = t & 127;
  float O0 = 0.f, O1 = 0.f, O2 = 0.f, O3 = 0.f, l = 0.f;
#pragma unroll
  for (int s = 0; s < 4; ++s) {
    size_t p = (((size_t)s * 8 + b) * 16 + qt) * 128 + r;
    l += lsum[p];
    ushort4 ov = *(const ushort4*)&Op[p * 64 + h4];
    O0 += bf2f(ov.x); O1 += bf2f(ov.y); O2 += bf2f(ov.z); O3 += bf2f(ov.w);
  }
  float inv = 1.0f / l;
  float4 res = make_float4(O0 * inv, O1 * inv, O2 * inv, O3 * inv);
  *(float4*)&out[(size_t)row * H_ + h4] = res;
}

extern "C" void kernel_launch(void* const* d_in, const int* in_sizes, int n_in,
                              void* d_out, int out_size, void* d_ws, size_t ws_size,
                              hipStream_t stream) {
  const float* x  = (const float*)d_in[0];
  const float* wq = (const float*)d_in[1];
  const float* wk = (const float*)d_in[2];
  const float* wv = (const float*)d_in[3];
  float* out = (float*)d_out;

  char* ws = (char*)d_ws;
  unsigned short* wf = (unsigned short*)ws;                    // 393216 B
  unsigned short* qb = (unsigned short*)(ws + 393216);         // 2097152 B
  unsigned short* kf = (unsigned short*)(ws + 2490368);        // 2097152 B (frag-ready)
  unsigned short* vf = (unsigned short*)(ws + 4587520);        // 2097152 B (frag-ready)
  unsigned short* Op = (unsigned short*)(ws + 6684672);        // 8388608 B (4 splits)
  float*          ls = (float*)(ws + 15073280);                // 262144 B (total 15335424)

  conv_w<<<96, 256, 0, stream>>>(wq, wk, wv, wf);
  qkv_proj<<<512, 256, 0, stream>>>(x, wf, qb, kf, vf);
  attn<<<dim3(16, 8, 4), 256, 0, stream>>>(qb, kf, vf, Op, ls);
  merge_splits<<<1024, 256, 0, stream>>>(Op, ls, out);
}

// Round 9
// 121.647 us; speedup vs baseline: 1.0149x; 1.0128x over previous
//
#include <hip/hip_runtime.h>

#define B_ 8
#define T_ 2048
#define C_ 1024
#define H_ 64

typedef __attribute__((ext_vector_type(8))) short short8;
typedef __attribute__((ext_vector_type(4))) float floatx4;
typedef __attribute__((ext_vector_type(4))) int intx4;

static __device__ __forceinline__ unsigned short f2bf(float f) {
  unsigned int u = __builtin_bit_cast(unsigned int, f);
  u += 0x7FFFu + ((u >> 16) & 1u);   // RNE
  return (unsigned short)(u >> 16);
}
static __device__ __forceinline__ float bf2f(unsigned short u) {
  return __builtin_bit_cast(float, ((unsigned int)u) << 16);
}
static __device__ __forceinline__ unsigned int fbits(float f) {
  return __builtin_bit_cast(unsigned int, f);
}

typedef const __attribute__((address_space(1))) unsigned int* gp1_t;
typedef __attribute__((address_space(3))) unsigned int* lp3_t;
static __device__ __forceinline__ void gl_lds16(const void* g, void* l) {
  __builtin_amdgcn_global_load_lds((gp1_t)g, (lp3_t)l, 16, 0, 0);
}

// ---------------------------------------------------------------------------
// Kernel 0: W fp32 -> Wf FRAGMENT-READY bf16 (unchanged).
// ---------------------------------------------------------------------------
__global__ __launch_bounds__(256) void conv_w(const float* __restrict__ wq,
    const float* __restrict__ wk, const float* __restrict__ wv,
    unsigned short* __restrict__ wf) {
  int c = blockIdx.x * 256 + threadIdx.x;   // 24576 chunks
  int lane = c & 63;
  int t = c >> 6;
  int ng = t % 12;
  int kk = t / 12;                           // kt*2+ks, 0..31
  int k0 = kk * 32 + (lane >> 4) * 8;
  int n = ng * 16 + (lane & 15);
  const float* src;
  int col;
  float scale = 1.0f;
  if (n < 64)       { src = wq; col = n;       scale = 0.03125f * 1.44269504088896340736f; }
  else if (n < 128) { src = wk; col = n - 64;  }
  else              { src = wv; col = n - 128; }
  unsigned short o[8];
#pragma unroll
  for (int j = 0; j < 8; ++j) o[j] = f2bf(src[(size_t)(k0 + j) * H_ + col] * scale);
  *(uint4*)&wf[(size_t)c * 8] = *(const uint4*)o;
}

// ---------------------------------------------------------------------------
// Kernel 1: QKV projection (unchanged).
// V epilogue writes Vf k-PERMUTED to match the swapped-QK^T P fragment.
// ---------------------------------------------------------------------------
__global__ __launch_bounds__(256, 4) void qkv_proj(
    const float* __restrict__ x, const unsigned short* __restrict__ wf,
    unsigned short* __restrict__ qo, unsigned short* __restrict__ kf,
    unsigned short* __restrict__ vf) {
  __shared__ float XL[2][4096];   // 2 x (32 rows x 128 fp32) = 32 KB
  int tid = threadIdx.x;
  int wave = tid >> 6, lane = tid & 63;
  int lane4 = lane & 15, quad = lane >> 4;
  int m0 = blockIdx.x * 32;
  int ph0 = blockIdx.x & 7;       // per-block K-order rotation

  // stage one phase (32 rows x 128 floats = 1024 16B-chunks, 4 insts/thread)
  auto stage_ph = [&](int phr, int buf) {
#pragma unroll
    for (int j = 0; j < 4; ++j) {
      int c = (wave * 4 + j) * 64 + lane;    // chunk id 0..1023
      int r = c >> 5, pc = c & 31;           // 32 chunks per row
      int cl = (pc & ~7) | ((pc ^ (r & 7)) & 7);
      gl_lds16(&x[(size_t)(m0 + r) * C_ + phr * 128 + cl * 4], &XL[buf][c * 4]);
    }
  };

  floatx4 acc[2][3];
#pragma unroll
  for (int mt = 0; mt < 2; ++mt)
#pragma unroll
    for (int nt = 0; nt < 3; ++nt) acc[mt][nt] = (floatx4)0.0f;

  stage_ph(ph0, 0);
  __syncthreads();

  for (int ph = 0; ph < 8; ++ph) {
    int buf = ph & 1;
    if (ph < 7) stage_ph((ph + 1 + ph0) & 7, buf ^ 1);   // async prefetch
    int phr = (ph + ph0) & 7;
#pragma unroll
    for (int sl = 0; sl < 4; ++sl) {
      int s = phr * 4 + sl;            // global ks-step, 0..31
      short8 b[3];
#pragma unroll
      for (int nt = 0; nt < 3; ++nt)
        b[nt] = *(const short8*)&wf[(size_t)(s * 12 + wave * 3 + nt) * 512 + lane * 8];
      short8 a[2];
#pragma unroll
      for (int mt = 0; mt < 2; ++mt) {
        int r = mt * 16 + lane4;
        int c0 = sl * 8 + quad * 2;    // phase-local float4-chunk, 0..31
        int pc0 = (c0 & ~7) | ((c0 ^ (r & 7)) & 7);
        int pc1 = ((c0 + 1) & ~7) | (((c0 + 1) ^ (r & 7)) & 7);
        float4 f0 = *(const float4*)&XL[buf][r * 128 + pc0 * 4];
        float4 f1 = *(const float4*)&XL[buf][r * 128 + pc1 * 4];
        intx4 pk;
        pk[0] = (int)__builtin_amdgcn_perm(fbits(f0.y), fbits(f0.x), 0x07060302u);
        pk[1] = (int)__builtin_amdgcn_perm(fbits(f0.w), fbits(f0.z), 0x07060302u);
        pk[2] = (int)__builtin_amdgcn_perm(fbits(f1.y), fbits(f1.x), 0x07060302u);
        pk[3] = (int)__builtin_amdgcn_perm(fbits(f1.w), fbits(f1.z), 0x07060302u);
        a[mt] = __builtin_bit_cast(short8, pk);
      }
#pragma unroll
      for (int mt = 0; mt < 2; ++mt)
#pragma unroll
        for (int nt = 0; nt < 3; ++nt)
          acc[mt][nt] = __builtin_amdgcn_mfma_f32_16x16x32_bf16(a[mt], b[nt], acc[mt][nt], 0, 0, 0);
    }
    __syncthreads();   // prefetch landed + all waves done with buf
  }

  // ---- epilogue: q direct; K,V via LDS into fragment-ready layouts ----
  unsigned short* VTB = (unsigned short*)&XL[0][0];   // [64 h][40] bf16 (V^T)
  unsigned short* KB  = VTB + 5120;                   // [32 t][72] bf16
#pragma unroll
  for (int mt = 0; mt < 2; ++mt)
#pragma unroll
    for (int nt = 0; nt < 3; ++nt) {
      int n = wave * 48 + nt * 16 + lane4;
#pragma unroll
      for (int rr = 0; rr < 4; ++rr) {
        unsigned short val = f2bf(acc[mt][nt][rr]);
        int lrow = mt * 16 + quad * 4 + rr;
        if (n < 64)       qo[(size_t)(m0 + lrow) * H_ + n] = val;
        else if (n < 128) KB[lrow * 72 + (n - 64)] = val;
        else              VTB[(n - 128) * 40 + lrow] = val;
      }
    }
  __syncthreads();
  {
    int bb = m0 >> 11, t0 = m0 & 2047;
    int st = t0 >> 6, off = t0 & 63;
    // K: 256 chunks (ks x ctl x 64 lanes)
    int ks = tid >> 7, ctl = (tid >> 6) & 1, ln = tid & 63;
    int ct = (off >> 4) + ctl;
    int tl = ctl * 16 + (ln & 15);
    int h0 = ks * 32 + (ln >> 4) * 8;
    uint4 kd = *(const uint4*)&KB[tl * 72 + h0];
    *(uint4*)&kf[((size_t)((bb * 32 + st) * 2 + ks) * 4 + ct) * 512 + ln * 8] = kd;
    // V: 256 chunks (nt x 64 lanes), ks fixed = off>>5; k-permuted frag:
    // slot (qs, j<4) = t 4*qs+j ; slot (qs, j>=4) = t 16+4*qs+(j-4)
    int nt = tid >> 6, l4 = tid & 15, qs = (tid >> 4) & 3;
    int ksv = off >> 5;
    uint2 vlo = *(const uint2*)&VTB[(nt * 16 + l4) * 40 + qs * 4];
    uint2 vhi = *(const uint2*)&VTB[(nt * 16 + l4) * 40 + 16 + qs * 4];
    uint4 vd = make_uint4(vlo.x, vlo.y, vhi.x, vhi.y);
    *(uint4*)&vf[((size_t)((bb * 32 + st) * 2 + ksv) * 4 + nt) * 512 + (tid & 63) * 8] = vd;
  }
}

// ---------------------------------------------------------------------------
// Kernel 2: causal flash attention -- EXACT R19 (the measured best, 121.6):
// split-4, in-register fixed-max softmax via swapped QK^T + k-permuted Vf,
// counted-vmcnt 3-buffer pipeline, qt<->15-qt dispatch pairing, 512 threads.
// R20 (1-block/CU sequential pairing) and R21 (2-stripe ILP at 256 threads)
// both regressed ~1.5us: attn is TLP-bound at 16 waves/CU; this shape is
// the local optimum. Reverted verbatim.
// ---------------------------------------------------------------------------
__global__ __launch_bounds__(512, 4) void attn(
    const unsigned short* __restrict__ qi, const unsigned short* __restrict__ Kf,
    const unsigned short* __restrict__ Vf, unsigned short* __restrict__ Op,
    float* __restrict__ lsum) {
  __shared__ unsigned short KV[3][8192];   // [buf][ K: 0..4095 | V: 4096..8191 ]

  int tid = threadIdx.x;
  int wave = tid >> 6, lane = tid & 63;
  int lane4 = lane & 15, quad = lane >> 4;
  int split = blockIdx.z;
  int qt = (split < 2) ? (15 - (int)blockIdx.x) : (int)blockIdx.x;
  int b = blockIdx.y;
  int qb = qt * 128;
  int base = b * T_;

  int ntile = 2 * qt + 2;
  int sBeg = (split * ntile) >> 2;
  int sEnd = ((split + 1) * ntile) >> 2;
  int last = sEnd - 1;

  short8 aq[2];
#pragma unroll
  for (int ks = 0; ks < 2; ++ks)
    aq[ks] = *(const short8*)&qi[(size_t)(base + qb + wave * 16 + lane4) * H_ + ks * 32 + quad * 8];

  float lsumv = 0.0f;
  floatx4 o[4];
#pragma unroll
  for (int nt = 0; nt < 4; ++nt) o[nt] = (floatx4)0.0f;

  // stage one 64-row K/V tile (8 KB + 8 KB) into KV[bf]; 2 insts/thread.
  auto stage = [&](int st, int bf) {
    size_t tb = (size_t)(b * 32 + st) * 4096;
    gl_lds16(&Kf[tb + (size_t)tid * 8], &KV[bf][tid * 8]);
    gl_lds16(&Vf[tb + (size_t)tid * 8], &KV[bf][4096 + tid * 8]);
  };

  if (sBeg < sEnd) {
    // depth-2 prologue (clamped: redundant re-stage keeps counts uniform)
    stage(sBeg, 0);
    {
      int s1 = sBeg + 1 <= last ? sBeg + 1 : last;
      stage(s1, 1);
    }

    for (int it = 0; it < sEnd - sBeg; ++it) {
      int st = sBeg + it;
      int buf = it % 3;

      // stage(st) landed (>=2 newer gl_lds exist); align all waves.
      asm volatile("s_waitcnt vmcnt(2)" ::: "memory");
      __builtin_amdgcn_sched_barrier(0);
      __builtin_amdgcn_s_barrier();

      // issue stage(st+2): overwrites the buffer last read in iter it-1,
      // which every wave finished before the barrier above.
      {
        int s2 = st + 2 <= last ? st + 2 : last;
        stage(s2, (it + 2) % 3);
      }

      // S^T = K . Q^T : lane holds S[kcol = ct*16+quad*4+r][qrow = lane4]
      floatx4 sacc[4];
#pragma unroll
      for (int ct = 0; ct < 4; ++ct) sacc[ct] = (floatx4)0.0f;
      __builtin_amdgcn_s_setprio(1);
#pragma unroll
      for (int ks = 0; ks < 2; ++ks)
#pragma unroll
        for (int ct = 0; ct < 4; ++ct) {
          short8 bk = *(const short8*)&KV[buf][(ks * 4 + ct) * 512 + lane * 8];
          sacc[ct] = __builtin_amdgcn_mfma_f32_16x16x32_bf16(bk, aq[ks], sacc[ct], 0, 0, 0);
        }
      __builtin_amdgcn_s_setprio(0);

      if (st >= 2 * qt) {   // the two diagonal-crossing tiles: absolute mask
        int qrow = qb + wave * 16 + lane4;
#pragma unroll
        for (int ct = 0; ct < 4; ++ct)
#pragma unroll
          for (int r = 0; r < 4; ++r) {
            int scol = st * 64 + ct * 16 + quad * 4 + r;
            if (scol > qrow) sacc[ct][r] = -3.0e38f;
          }
      }

      // fixed-max softmax in registers: p = exp2(s - 8); pack bf16 via perm
      unsigned int pk[4][2];
#pragma unroll
      for (int ct = 0; ct < 4; ++ct) {
        float p0 = exp2f(sacc[ct][0] - 8.0f);
        float p1 = exp2f(sacc[ct][1] - 8.0f);
        float p2 = exp2f(sacc[ct][2] - 8.0f);
        float p3 = exp2f(sacc[ct][3] - 8.0f);
        lsumv += (p0 + p1) + (p2 + p3);
        pk[ct][0] = __builtin_amdgcn_perm(fbits(p1), fbits(p0), 0x07060302u);
        pk[ct][1] = __builtin_amdgcn_perm(fbits(p3), fbits(p2), 0x07060302u);
      }

      // O += P V  (pa register-resident; Vf k-order matches pk layout)
      __builtin_amdgcn_s_setprio(1);
#pragma unroll
      for (int ks = 0; ks < 2; ++ks) {
        intx4 pai;
        pai[0] = (int)pk[2 * ks][0];
        pai[1] = (int)pk[2 * ks][1];
        pai[2] = (int)pk[2 * ks + 1][0];
        pai[3] = (int)pk[2 * ks + 1][1];
        short8 pa = __builtin_bit_cast(short8, pai);
#pragma unroll
        for (int nt = 0; nt < 4; ++nt) {
          short8 bv = *(const short8*)&KV[buf][4096 + (ks * 4 + nt) * 512 + lane * 8];
          o[nt] = __builtin_amdgcn_mfma_f32_16x16x32_bf16(pa, bv, o[nt], 0, 0, 0);
        }
      }
      __builtin_amdgcn_s_setprio(0);
    }
  }

  // l-reduce: quads {0,1,2,3} of each lane4 hold partials of the same q-row
  lsumv += __shfl_xor(lsumv, 16);
  lsumv += __shfl_xor(lsumv, 32);

  size_t pbase = (((size_t)split * 8 + b) * 16 + qt) * 128;
#pragma unroll
  for (int r = 0; r < 4; ++r) {
    int row = wave * 16 + quad * 4 + r;
#pragma unroll
    for (int nt = 0; nt < 4; ++nt)
      Op[(pbase + row) * 64 + nt * 16 + lane4] = f2bf(o[nt][r]);
  }
  if (quad == 0) lsum[pbase + wave * 16 + lane4] = lsumv;
}

// ---------------------------------------------------------------------------
// Kernel 3: merge the 4 key-range splits: out = sum(O_i) / sum(l_i).
// R22 CHANGE (vectorize, G13): was 262K threads x 4 scattered dwordx2 Op
// reads + dword-pair stores -- instruction-heavy for a pure streaming op at
// 2x its 2.0us traffic floor (12.7 MB @ 6.3 TB/s). Now one thread per 8-wide
// h-half: 131K threads (512 blocks), 4 x ushort8 (dwordx4) reads, 2 x float4
// stores. Half the threads, double read width, half the store count.
// Same per-element arithmetic order -> absmax unchanged.
// ---------------------------------------------------------------------------
__global__ __launch_bounds__(256) void merge_splits(
    const unsigned short* __restrict__ Op, const float* __restrict__ lsum,
    float* __restrict__ out) {
  int idx = blockIdx.x * 256 + threadIdx.x;   // 131072 threads
  int row = idx >> 3;
  int h8 = (idx & 7) * 8;
  int b = row >> 11, t = row & 2047;
  int qt = t >> 7, r = t & 127;
  float O[8];
#pragma unroll
  for (int j = 0; j < 8; ++j) O[j] = 0.0f;
  float l = 0.0f;
#pragma unroll
  for (int s = 0; s < 4; ++s) {
    size_t p = (((size_t)s * 8 + b) * 16 + qt) * 128 + r;
    l += lsum[p];
    uint4 ov = *(const uint4*)&Op[p * 64 + h8];
    O[0] += bf2f((unsigned short)(ov.x & 0xFFFFu));
    O[1] += bf2f((unsigned short)(ov.x >> 16));
    O[2] += bf2f((unsigned short)(ov.y & 0xFFFFu));
    O[3] += bf2f((unsigned short)(ov.y >> 16));
    O[4] += bf2f((unsigned short)(ov.z & 0xFFFFu));
    O[5] += bf2f((unsigned short)(ov.z >> 16));
    O[6] += bf2f((unsigned short)(ov.w & 0xFFFFu));
    O[7] += bf2f((unsigned short)(ov.w >> 16));
  }
  float inv = 1.0f / l;
  float4 r0 = make_float4(O[0] * inv, O[1] * inv, O[2] * inv, O[3] * inv);
  float4 r1 = make_float4(O[4] * inv, O[5] * inv, O[6] * inv, O[7] * inv);
  *(float4*)&out[(size_t)row * H_ + h8] = r0;
  *(float4*)&out[(size_t)row * H_ + h8 + 4] = r1;
}

extern "C" void kernel_launch(void* const* d_in, const int* in_sizes, int n_in,
                              void* d_out, int out_size, void* d_ws, size_t ws_size,
                              hipStream_t stream) {
  const float* x  = (const float*)d_in[0];
  const float* wq = (const float*)d_in[1];
  const float* wk = (const float*)d_in[2];
  const float* wv = (const float*)d_in[3];
  float* out = (float*)d_out;

  char* ws = (char*)d_ws;
  unsigned short* wf = (unsigned short*)ws;                    // 393216 B
  unsigned short* qb = (unsigned short*)(ws + 393216);         // 2097152 B
  unsigned short* kf = (unsigned short*)(ws + 2490368);        // 2097152 B (frag-ready)
  unsigned short* vf = (unsigned short*)(ws + 4587520);        // 2097152 B (frag-ready)
  unsigned short* Op = (unsigned short*)(ws + 6684672);        // 8388608 B (4 splits)
  float*          ls = (float*)(ws + 15073280);                // 262144 B (total 15335424)

  conv_w<<<96, 256, 0, stream>>>(wq, wk, wv, wf);
  qkv_proj<<<512, 256, 0, stream>>>(x, wf, qb, kf, vf);
  attn<<<dim3(16, 8, 4), 512, 0, stream>>>(qb, kf, vf, Op, ls);
  merge_splits<<<512, 256, 0, stream>>>(Op, ls, out);
}